// Round 1
// baseline (209.602 us; speedup 1.0000x reference)
//
#include <hip/hip_runtime.h>
#include <hip/hip_bf16.h>

#define BSZ 512
#define DIM 768
#define NTYPES 16
#define MARGIN 1.0f
#define NANCH 16              // anchors per block
#define NBLK (BSZ / NANCH)    // 32 blocks, 1 per CU
#define KSEG 32               // k-columns per staged segment
#define NSEG (DIM / KSEG)     // 24
#define BPITCH 40             // 32+8 ushorts = 80 B rows (odd # of 16B units -> 2-way max)
#define APITCH 776            // 768+8 ushorts = 1552 B rows (97 x 16B, odd -> 2-way max)
#define DPITCH 514            // dist pitch in floats (stride ≡ 2 banks -> q enters bank formula)

typedef short bf16x8 __attribute__((ext_vector_type(8)));
typedef float f32x4 __attribute__((ext_vector_type(4)));

// ---------------------------------------------------------------------------
// Single fused kernel (replaces dot_partial_kernel + triplet_kernel).
// Rationale: the 256 MiB workspace poison fill (~40.6us) is a fixed harness
// cost; the remaining ~33us of the 73.5us baseline is dominated by
// per-dispatch overhead (k1+k2 arithmetic is only ~4-6us of real work).
// So: ONE kernel after the fill, zero workspace traffic.
//
// Structure: 32 blocks x 256 threads; block b owns anchors [16b,16b+16).
//  - Full-K gram strip G[16][512] via mfma_f32_16x16x32_bf16 (layouts copied
//    verbatim from the verified k1: A/B lane m=lane&15 reads 8 consecutive k
//    at k0=8*(lane>>4); C/D col=lane&15 (j-in-tile), row=4*(lane>>4)+reg
//    (anchor)).  B staged in 24 double-buffered 32-col bf16 segments
//    (1 barrier/segment); fp32 row norms accumulated for free in the staging
//    path (4 lanes/row -> shfl_xor reduce -> single owner writes nrm[row]).
//  - d(a,j) = sqrt(max(na+nrm[j]-2G,0)) into LDS, then per-anchor ballot
//    compaction + wave-striped |P|x|N| scan (proven k2 code).
//  - out is poisoned each launch: block 0's FIRST instruction is
//    atomicExch(out,0).  Workers' single atomicAdd comes after >=10us of
//    staging+MFMA+scan; all 32 blocks dispatch within ~1us on an idle GPU
//    -> >=9us ordering margin at the same atomic coherence point (intra-
//    kernel analog of the cross-kernel zero proven R6-R13).
//  - Precision: same bf16 gram quantization as the absmax-0.0 baseline.
//    fp32 norms (instead of bf16 diag) make d(a,a) inexact by <=~0.5, but
//    those terms are clamp(d(a,a)+1-dn) with dn~39 -> exactly 0 either way.
// LDS total ~148 KB (fits 160 KB/CU; grid=32 so 1 block/CU is fine).
// ---------------------------------------------------------------------------
__global__ __launch_bounds__(256) void fused_triplet_kernel(
    const float* __restrict__ emb,
    const int* __restrict__ types,
    float* __restrict__ out)
{
    const int tid = threadIdx.x;
    const int b = blockIdx.x;

    // out is poisoned each launch; zero it before any worker can add (see note)
    if (b == 0 && tid == 0) atomicExch(out, 0.0f);

    __shared__ ushort sB[2][BSZ][BPITCH];     // 81920 B  (double-buffered segment)
    __shared__ ushort sA[NANCH][APITCH];      // 24832 B  (anchors, full K)
    __shared__ float dst[NANCH][DPITCH];      // 32896 B  (distances)
    __shared__ float nrm[BSZ];                //  2048 B  (fp32 row norms)
    __shared__ float na[NANCH];               //    64 B  (anchor norms)
    __shared__ float pos[BSZ], neg[BSZ];      //  4096 B
    __shared__ int   stypes[BSZ];             //  2048 B
    __shared__ int   cnt[NTYPES];
    __shared__ int   npA[NANCH], nnA[NANCH];
    __shared__ float wsum[4];

    // ---- phase A: stage 16 anchor rows (full K) -> bf16 sA + fp32 na -------
    {
        const int row = tid >> 4;             // 0..15, fixed per thread
        const int c0 = tid & 15;
        const float* src = emb + (size_t)(b * NANCH + row) * DIM;
        float qn = 0.f;
        #pragma unroll
        for (int i = 0; i < 12; ++i) {
            const int c4 = c0 + 16 * i;       // 0..191, 256 B coalesced / 16 lanes
            const float4 v = *(const float4*)(src + c4 * 4);
            qn += v.x * v.x + v.y * v.y + v.z * v.z + v.w * v.w;
            __hip_bfloat162 h0 = __float22bfloat162_rn(make_float2(v.x, v.y));
            __hip_bfloat162 h1 = __float22bfloat162_rn(make_float2(v.z, v.w));
            unsigned u0, u1;
            __builtin_memcpy(&u0, &h0, 4);
            __builtin_memcpy(&u1, &h1, 4);
            *(uint2*)&sA[row][c4 * 4] = make_uint2(u0, u1);
        }
        qn += __shfl_xor(qn, 1); qn += __shfl_xor(qn, 2);
        qn += __shfl_xor(qn, 4); qn += __shfl_xor(qn, 8);
        if (c0 == 0) na[row] = qn;
    }
    if (tid < NTYPES) cnt[tid] = 0;
    if (tid < NANCH) { npA[tid] = 0; nnA[tid] = 0; }
    for (int j = tid; j < BSZ; j += 256) stypes[j] = types[j];

    // ---- B-segment stage: 512 rows x KSEG cols -> bf16, fp32 norm partials -
    auto stageB = [&](int s, int buf) {
        const int rsub = tid >> 2;            // 4 lanes per row
        const int c0 = tid & 3;
        #pragma unroll
        for (int p = 0; p < 8; ++p) {
            const int row = p * 64 + rsub;
            const float* src = emb + (size_t)row * DIM + s * KSEG;
            float qn = 0.f;
            #pragma unroll
            for (int i = 0; i < 2; ++i) {
                const int c4 = c0 + 4 * i;    // 0..7
                const float4 v = *(const float4*)(src + c4 * 4);
                qn += v.x * v.x + v.y * v.y + v.z * v.z + v.w * v.w;
                __hip_bfloat162 h0 = __float22bfloat162_rn(make_float2(v.x, v.y));
                __hip_bfloat162 h1 = __float22bfloat162_rn(make_float2(v.z, v.w));
                unsigned u0, u1;
                __builtin_memcpy(&u0, &h0, 4);
                __builtin_memcpy(&u1, &h1, 4);
                *(uint2*)&sB[buf][row][c4 * 4] = make_uint2(u0, u1);
            }
            qn += __shfl_xor(qn, 1); qn += __shfl_xor(qn, 2);
            // single consistent owner per row across all segments: plain add, no race
            if (c0 == 0) nrm[row] = (s == 0) ? qn : (nrm[row] + qn);
        }
    };

    // ---- main K loop: double-buffered staging || MFMA, 1 barrier/segment ---
    const int lane = tid & 63;
    const int w = tid >> 6;                   // wave 0..3 -> j in [w*128, w*128+128)
    const int m = lane & 15;
    const int qq = lane >> 4;                 // 0..3

    f32x4 acc[8];
    #pragma unroll
    for (int t = 0; t < 8; ++t) acc[t] = (f32x4){0.f, 0.f, 0.f, 0.f};

    stageB(0, 0);
    __syncthreads();

    #pragma unroll 2
    for (int s = 0; s < NSEG; ++s) {
        if (s + 1 < NSEG) stageB(s + 1, (s + 1) & 1);   // prefetch next buffer
        // MFMA on current buffer: 8 j-tiles x 1 k-chunk of 32
        {
            const ushort* ap = &sA[m][s * KSEG + qq * 8];
            const bf16x8 af = *(const bf16x8*)ap;
            const ushort* bp = &sB[s & 1][w * 128 + m][qq * 8];
            #pragma unroll
            for (int t = 0; t < 8; ++t) {
                const bf16x8 bf = *(const bf16x8*)(bp + t * 16 * BPITCH);
                acc[t] = __builtin_amdgcn_mfma_f32_16x16x32_bf16(af, bf, acc[t], 0, 0, 0);
            }
        }
        __syncthreads();
    }

    // ---- distances from acc (C/D: col=m -> j-in-tile, row=4q+r -> anchor) --
    #pragma unroll
    for (int t = 0; t < 8; ++t) {
        const int j = w * 128 + t * 16 + m;
        const float nj = nrm[j];
        #pragma unroll
        for (int r = 0; r < 4; ++r) {
            const int ar = 4 * qq + r;
            const float sq = na[ar] + nj - 2.f * acc[t][r];
            dst[ar][j] = sqrtf(fmaxf(sq, 0.f));
        }
    }
    for (int j = tid; j < BSZ; j += 256) atomicAdd(&cnt[stypes[j]], 1);

    // ---- per-anchor compaction + wave-striped |P|x|N| scan -----------------
    float local = 0.f;
    for (int a = 0; a < NANCH; ++a) {
        __syncthreads();                      // dst ready / prev scan done
        const int ta = stypes[b * NANCH + a];
        #pragma unroll
        for (int jj = 0; jj < 2; ++jj) {
            const int j = jj * 256 + tid;
            const float d = dst[a][j];
            const bool isp = (stypes[j] == ta);
            const unsigned long long mm = __ballot(isp);
            const unsigned long long below = mm & ((1ull << lane) - 1ull);
            const int cp = __popcll(mm);
            int basep = 0, basen = 0;
            if (lane == 0) {
                basep = atomicAdd(&npA[a], cp);
                basen = atomicAdd(&nnA[a], 64 - cp);
            }
            basep = __shfl(basep, 0);
            basen = __shfl(basen, 0);
            const int pb = (int)__popcll(below);
            if (isp) pos[basep + pb] = d;
            else     neg[basen + (lane - pb)] = d;
        }
        __syncthreads();
        const int np = npA[a], nn = nnA[a];
        for (int pi = w; pi < np; pi += 4) {  // wave-striped: amortizes loop overhead
            const float dpm = pos[pi] + MARGIN;
            for (int n = lane; n < nn; n += 64)
                local += fmaxf(dpm - neg[n], 0.f);
        }
    }

    // ---- block reduce + single device atomic -------------------------------
    #pragma unroll
    for (int off = 32; off > 0; off >>= 1) local += __shfl_down(local, off);
    if (lane == 0) wsum[w] = local;
    __syncthreads();
    if (tid == 0) {
        long long V = 0;
        #pragma unroll
        for (int t = 0; t < NTYPES; ++t) {
            long long c = cnt[t];
            V += c * c * (long long)(BSZ - c);
        }
        double bs = (double)wsum[0] + (double)wsum[1] + (double)wsum[2] + (double)wsum[3];
        float contrib = (float)(bs / (double)V);
        if (b == 0) {
            const long long B3 = (long long)BSZ * BSZ * BSZ;
            contrib += (float)((double)(B3 - V) * (double)MARGIN / (double)V);
        }
        atomicAdd(out, contrib);              // plain relaxed device atomic
    }
}

extern "C" void kernel_launch(void* const* d_in, const int* in_sizes, int n_in,
                              void* d_out, int out_size, void* d_ws, size_t ws_size,
                              hipStream_t stream) {
    const int* types = (const int*)d_in[0];
    const float* emb = (const float*)d_in[1];
    float* out = (float*)d_out;
    (void)d_ws; (void)ws_size;                // workspace intentionally unused
    fused_triplet_kernel<<<NBLK, 256, 0, stream>>>(emb, types, out);
}

// Round 2
// 124.721 us; speedup vs baseline: 1.6806x; 1.6806x over previous
//
#include <hip/hip_runtime.h>
#include <hip/hip_bf16.h>

#define BSZ 512
#define DIM 768
#define NTYPES 16
#define MARGIN 1.0f
#define NANCH 16              // anchors per block
#define NBLK (BSZ / NANCH)    // 32 blocks (1 CU each)
#define THREADS 1024          // 16 waves -> 4 waves/SIMD (TLP for latency hiding)
#define NSEG (DIM / 32)       // 24 K-chunks of 32
#define DPITCH 514            // 514 % 8 == 2 -> 4*DPITCH ≡ 8 (mod 32): qq groups spread
                              // across banks {0,8,16,24}, m spans 16 -> 2-way max (free)

typedef short bf16x8 __attribute__((ext_vector_type(8)));
typedef float f32x4 __attribute__((ext_vector_type(4)));

// ---------------------------------------------------------------------------
// R2: single fused kernel, latency-tolerant rewrite of R1.
// R1 post-mortem: 158us at Occupancy 1.39% = 1 wave/SIMD on 32 CUs -> every
// L2/LDS latency serially exposed (24 barriered segments + runtime-bound LDS
// scan ~120cy/iter).  Fix: 16 waves/block (4/SIMD), ZERO barriers in the
// K-loop (MFMA fragments loaded straight from global + reg cvt to bf16; no
// sB staging), scan restructured so wave w owns anchor w with negatives
// staged in registers (pure-VALU inner loop, no LDS latency, no atomics).
//
// Work split: block b owns anchors [16b,16b+16); wave w owns j-strip
// [32w,32w+32) (2 MFMA 16x16x32 j-tiles, full K).  Fragment layouts verbatim
// from the verified kernels: A/B lane m=lane&15 holds 8 consecutive k at
// k0=8*(lane>>4); C/D col=m (j-in-tile), row=4*(lane>>4)+reg (anchor).
// fp32 row norms accumulated for free during the B loads (each lane covers
// k-slice qq of its row; shfl_xor 16/32 merges the 4 slices); anchor norms
// are just nrm[16b+ar] since anchors are j-rows too.
//
// out is poisoned each launch: block 0's first instruction is
// atomicExch(out,0); all worker atomicAdds happen after ~>=10us of work and
// all 32 blocks dispatch within ~1us (pattern passed R1, absmax 0.0).
// Numerics: bf16 gram + fp32 norms, identical to the absmax-0.0 R1 version
// (d(a,a) error <=~0.7 clamps away against d_neg~39 + margin).
// LDS ~70 KB; VGPR capped via __launch_bounds__(1024,4) -> <=128.
// ---------------------------------------------------------------------------

__device__ __forceinline__ bf16x8 pack8(float4 u, float4 v) {
    union { bf16x8 r; __hip_bfloat162 h[4]; } p;
    p.h[0] = __float22bfloat162_rn(make_float2(u.x, u.y));
    p.h[1] = __float22bfloat162_rn(make_float2(u.z, u.w));
    p.h[2] = __float22bfloat162_rn(make_float2(v.x, v.y));
    p.h[3] = __float22bfloat162_rn(make_float2(v.z, v.w));
    return p.r;
}

__global__ __launch_bounds__(THREADS, 4) void fused_triplet_kernel(
    const float* __restrict__ emb,
    const int* __restrict__ types,
    float* __restrict__ out)
{
    const int tid = threadIdx.x;
    const int b = blockIdx.x;

    // out is poisoned each launch; zero before any worker's add (see header)
    if (b == 0 && tid == 0) atomicExch(out, 0.0f);

    __shared__ float dst[NANCH][DPITCH];      // 32896 B distances d[a][j]
    __shared__ float posneg[NANCH][BSZ];      // 32768 B pos grows up, neg grows down
    __shared__ float nrm[BSZ];                //  2048 B fp32 row norms
    __shared__ int   stypes[BSZ];             //  2048 B
    __shared__ int   cnt[NTYPES];
    __shared__ float wsum[16];

    if (tid < NTYPES) cnt[tid] = 0;
    if (tid < BSZ) stypes[tid] = types[tid];

    const int lane = tid & 63;
    const int w = tid >> 6;                   // wave 0..15
    const int m = lane & 15;
    const int qq = lane >> 4;                 // k-slice 0..3
    const int jb = w * 32;                    // this wave's j-base

    // ---- barrier-free gram: direct global->reg->bf16 fragment loads -------
    const float* pa  = emb + (size_t)(b * NANCH + m) * DIM + qq * 8;  // anchor row m
    const float* pb0 = emb + (size_t)(jb + m) * DIM + qq * 8;         // j-tile 0
    const float* pb1 = emb + (size_t)(jb + 16 + m) * DIM + qq * 8;    // j-tile 1

    f32x4 acc0 = {0.f, 0.f, 0.f, 0.f};
    f32x4 acc1 = {0.f, 0.f, 0.f, 0.f};
    float qn0 = 0.f, qn1 = 0.f;

    #pragma unroll 4
    for (int s = 0; s < NSEG; ++s) {
        const float4 a0 = *(const float4*)(pa + s * 32);
        const float4 a1 = *(const float4*)(pa + s * 32 + 4);
        const float4 x0 = *(const float4*)(pb0 + s * 32);
        const float4 x1 = *(const float4*)(pb0 + s * 32 + 4);
        const float4 y0 = *(const float4*)(pb1 + s * 32);
        const float4 y1 = *(const float4*)(pb1 + s * 32 + 4);
        qn0 += x0.x*x0.x + x0.y*x0.y + x0.z*x0.z + x0.w*x0.w
             + x1.x*x1.x + x1.y*x1.y + x1.z*x1.z + x1.w*x1.w;
        qn1 += y0.x*y0.x + y0.y*y0.y + y0.z*y0.z + y0.w*y0.w
             + y1.x*y1.x + y1.y*y1.y + y1.z*y1.z + y1.w*y1.w;
        const bf16x8 af = pack8(a0, a1);
        acc0 = __builtin_amdgcn_mfma_f32_16x16x32_bf16(af, pack8(x0, x1), acc0, 0, 0, 0);
        acc1 = __builtin_amdgcn_mfma_f32_16x16x32_bf16(af, pack8(y0, y1), acc1, 0, 0, 0);
    }

    // ---- fp32 row norms: merge the 4 k-slices (lanes m, m+16, m+32, m+48) --
    qn0 += __shfl_xor(qn0, 16); qn0 += __shfl_xor(qn0, 32);
    qn1 += __shfl_xor(qn1, 16); qn1 += __shfl_xor(qn1, 32);
    if (qq == 0) { nrm[jb + m] = qn0; nrm[jb + 16 + m] = qn1; }

    __syncthreads();                          // nrm + stypes complete

    if (tid < BSZ) atomicAdd(&cnt[stypes[tid]], 1);

    // ---- distances (C/D: col=m -> j-in-tile, row=4qq+r -> anchor) ----------
    const float nj0 = nrm[jb + m];
    const float nj1 = nrm[jb + 16 + m];
    #pragma unroll
    for (int r = 0; r < 4; ++r) {
        const int ar = 4 * qq + r;
        const float nna = nrm[b * NANCH + ar];      // anchor is also a j-row
        dst[ar][jb + m]      = sqrtf(fmaxf(nna + nj0 - 2.f * acc0[r], 0.f));
        dst[ar][jb + 16 + m] = sqrtf(fmaxf(nna + nj1 - 2.f * acc1[r], 0.f));
    }

    __syncthreads();                          // dst + cnt complete

    // ---- wave w owns anchor w: ballot compaction (no atomics) + reg scan ---
    const int ta = stypes[b * NANCH + w];
    float* pn = posneg[w];
    int np = 0, nn = 0;
    #pragma unroll
    for (int c = 0; c < 8; ++c) {
        const int j = c * 64 + lane;
        const float d = dst[w][j];
        const bool isp = (stypes[j] == ta);
        const unsigned long long mm = __ballot(isp);
        const int cp = __popcll(mm);
        const int pb = (int)__popcll(mm & ((1ull << lane) - 1ull));
        if (isp) pn[np + pb] = d;                       // positives grow up
        else     pn[BSZ - 1 - (nn + (lane - pb))] = d;  // negatives grow down
        np += cp; nn += 64 - cp;                        // uniform (ballot-derived)
    }
    __syncthreads();                          // pn[w] fully written (own wave only,
                                              // but cheap and keeps ds ordering simple)

    // negatives -> 8 registers once; inner loop is pure VALU
    float nr[8];
    #pragma unroll
    for (int c = 0; c < 8; ++c) {
        const int n = c * 64 + lane;
        nr[c] = (n < nn) ? pn[BSZ - 1 - n] : 3.0e38f;   // sentinel -> contributes 0
    }
    float local = 0.f;
    for (int pi = 0; pi < np; ++pi) {
        const float dpm = pn[pi] + MARGIN;              // broadcast LDS read
        #pragma unroll
        for (int c = 0; c < 8; ++c)
            local += fmaxf(dpm - nr[c], 0.f);
    }

    // ---- block reduce + single device atomic -------------------------------
    #pragma unroll
    for (int off = 32; off > 0; off >>= 1) local += __shfl_down(local, off);
    if (lane == 0) wsum[w] = local;
    __syncthreads();
    if (tid == 0) {
        long long V = 0;
        #pragma unroll
        for (int t = 0; t < NTYPES; ++t) {
            long long c = cnt[t];
            V += c * c * (long long)(BSZ - c);
        }
        double bs = 0.0;
        #pragma unroll
        for (int i = 0; i < 16; ++i) bs += (double)wsum[i];
        float contrib = (float)(bs / (double)V);
        if (b == 0) {
            const long long B3 = (long long)BSZ * BSZ * BSZ;
            contrib += (float)((double)(B3 - V) * (double)MARGIN / (double)V);
        }
        atomicAdd(out, contrib);              // plain relaxed device atomic
    }
}

extern "C" void kernel_launch(void* const* d_in, const int* in_sizes, int n_in,
                              void* d_out, int out_size, void* d_ws, size_t ws_size,
                              hipStream_t stream) {
    const int* types = (const int*)d_in[0];
    const float* emb = (const float*)d_in[1];
    float* out = (float*)d_out;
    (void)d_ws; (void)ws_size;                // workspace intentionally unused
    fused_triplet_kernel<<<NBLK, THREADS, 0, stream>>>(emb, types, out);
}

// Round 3
// 71.070 us; speedup vs baseline: 2.9492x; 1.7549x over previous
//
#include <hip/hip_runtime.h>
#include <hip/hip_bf16.h>

#define BSZ 512
#define DIM 768
#define NTYPES 16
#define MARGIN 1.0f
#define PITCH 776   // ushorts/row: 1552 B ≡ 97×16B (odd) -> b128 reads spread
                    // uniformly over the 8 4-bank groups (m+q mod 8) = conflict-free

typedef short bf16x8 __attribute__((ext_vector_type(8)));
typedef float f32x4 __attribute__((ext_vector_type(4)));

// ---------------------------------------------------------------------------
// R3: back to the proven 2-kernel structure, reshaped from the R2 post-mortem.
// R2 lesson: a fused kernel where every block reads all 512 j-rows has a hard
// per-CU L1-port floor (~10.5us) and, at VGPR=64, 7x latency exposure on top
// (measured 72us).  Inter-block j-row sharing requires the kernel boundary
// (grid-sync acquire/release measured 7-50us in the prior session -> banned).
//
// k1 gram_kernel: 256 blocks = 16x16 tiles of 32x32, FULL K (no ksplit).
// Per block: stage 64 rows x 768 cols fp32->bf16 into LDS (192 KB global
// read; port floor 1.25us; all 256 CUs busy), one barrier, then each of 4
// waves computes one 16x16 output tile: 24 k-chunks of 32 via
// mfma_f32_16x16x32_bf16, split into even/odd accumulator chains for 2x ILP.
// Layouts verbatim from the verified baseline: A/B lane m=lane&15 holds 8
// consecutive k at k0=8*(lane>>4); C/D col=m, row=4*(lane>>4)+reg.
// Writes G[512][512] fp32 (1 MB) + diagonal -> nrm[512] (so d(a,a)==0
// exactly; bf16 gram numerics identical to the absmax-0.0 baseline).
// Block 0 zeroes the poisoned out[0] (cross-kernel visibility proven
// R6-R13 of the prior session).
//
// k2 triplet_kernel: 512 blocks x 256 thr (2 blocks/CU).  Reads G row a
// (2 KB) + nrm + types; d on the fly; baseline's proven ballot compaction
// into pos/neg LDS; then R2's register-staged negative scan (8 VGPRs/lane,
// pure-VALU inner loop) with positives striped across the 4 waves.  Local
// type histogram -> V; one plain device atomicAdd per block; block 0 adds
// the closed-form invalid-triplet term (B^3-V)*margin/V.
// ---------------------------------------------------------------------------

__global__ __launch_bounds__(256) void gram_kernel(
    const float* __restrict__ emb,
    float* __restrict__ G,
    float* __restrict__ nrm,
    float* __restrict__ out)
{
    const int tid = threadIdx.x;
    const int blk = blockIdx.x;
    const int ti = blk >> 4, tj = blk & 15;
    const int i0 = ti * 32, j0 = tj * 32;

    if (blk == 0 && tid == 0) out[0] = 0.f;   // out is poisoned each launch

    __shared__ ushort sR[64][PITCH];          // rows 0-31: i-rows, 32-63: j-rows

    // ---- stage 64 rows x 768 floats -> bf16 LDS (coalesced, 48 f4/thread) --
    #pragma unroll 12
    for (int it = 0; it < 48; ++it) {
        const int flat = it * 256 + tid;      // 0..12287
        const int row = flat / 192;           // 0..63
        const int c4 = flat - row * 192;      // 0..191
        const int grow = (row < 32) ? (i0 + row) : (j0 + row - 32);
        const float4 v = *(const float4*)(emb + (size_t)grow * DIM + c4 * 4);
        __hip_bfloat162 h0 = __float22bfloat162_rn(make_float2(v.x, v.y));
        __hip_bfloat162 h1 = __float22bfloat162_rn(make_float2(v.z, v.w));
        unsigned u0, u1;
        __builtin_memcpy(&u0, &h0, 4);
        __builtin_memcpy(&u1, &h1, 4);
        *(uint2*)&sR[row][c4 * 4] = make_uint2(u0, u1);
    }
    __syncthreads();

    // ---- wave w -> output quadrant (wr, wc); even/odd k chains for ILP -----
    const int lane = tid & 63;
    const int w = tid >> 6;
    const int wr = w >> 1, wc = w & 1;
    const int m = lane & 15;
    const int q = lane >> 4;

    const ushort* arow = &sR[wr * 16 + m][q * 8];
    const ushort* brow = &sR[32 + wc * 16 + m][q * 8];

    f32x4 acc_e = {0.f, 0.f, 0.f, 0.f};
    f32x4 acc_o = {0.f, 0.f, 0.f, 0.f};
    #pragma unroll
    for (int kc = 0; kc < 24; kc += 2) {
        const bf16x8 ae = *(const bf16x8*)(arow + kc * 32);
        const bf16x8 be = *(const bf16x8*)(brow + kc * 32);
        const bf16x8 ao = *(const bf16x8*)(arow + kc * 32 + 32);
        const bf16x8 bo = *(const bf16x8*)(brow + kc * 32 + 32);
        acc_e = __builtin_amdgcn_mfma_f32_16x16x32_bf16(ae, be, acc_e, 0, 0, 0);
        acc_o = __builtin_amdgcn_mfma_f32_16x16x32_bf16(ao, bo, acc_o, 0, 0, 0);
    }

    // ---- epilogue: C/D col=m, row=4q+r ------------------------------------
    const int gi = i0 + wr * 16 + 4 * q;
    const int gj = j0 + wc * 16 + m;
    float res[4];
    #pragma unroll
    for (int r = 0; r < 4; ++r) {
        res[r] = acc_e[r] + acc_o[r];
        G[(size_t)(gi + r) * BSZ + gj] = res[r];
    }
    // diagonal: tile-local row 4q+r == col m  ->  q==m>>2, r==m&3
    if (ti == tj && wr == wc && (m >> 2) == q)
        nrm[i0 + wr * 16 + m] = res[m & 3];
}

__global__ __launch_bounds__(256) void triplet_kernel(
    const float* __restrict__ G, const float* __restrict__ nrm,
    const int* __restrict__ types, float* __restrict__ out)
{
    const int a = blockIdx.x;
    const int tid = threadIdx.x;
    const int lane = tid & 63;
    const int w = tid >> 6;

    __shared__ float snrm[BSZ];
    __shared__ int   stypes[BSZ];
    __shared__ float pos[BSZ], neg[BSZ];
    __shared__ int   npos, nneg, cnt[NTYPES];
    __shared__ float wsum[4];

    if (tid == 0) { npos = 0; nneg = 0; }
    if (tid < NTYPES) cnt[tid] = 0;
    for (int j = tid; j < BSZ; j += 256) { stypes[j] = types[j]; snrm[j] = nrm[j]; }
    __syncthreads();

    const int ta = stypes[a];
    const float na = snrm[a];
    for (int j = tid; j < BSZ; j += 256) atomicAdd(&cnt[stypes[j]], 1);

    // ---- distance on the fly + ballot compaction (baseline-proven) --------
    #pragma unroll
    for (int jj = 0; jj < 2; ++jj) {
        const int j = jj * 256 + tid;
        const float g = G[(size_t)a * BSZ + j];
        const float d = sqrtf(fmaxf(na + snrm[j] - 2.f * g, 0.f));
        const bool isp = (stypes[j] == ta);
        const unsigned long long mm = __ballot(isp);
        const unsigned long long below = mm & ((1ull << lane) - 1ull);
        const int cp = __popcll(mm);
        int basep = 0, basen = 0;
        if (lane == 0) {
            basep = atomicAdd(&npos, cp);
            basen = atomicAdd(&nneg, 64 - cp);
        }
        basep = __shfl(basep, 0);
        basen = __shfl(basen, 0);
        const int pb = (int)__popcll(below);
        if (isp) pos[basep + pb] = d;
        else     neg[basen + (lane - pb)] = d;
    }
    __syncthreads();
    const int np = npos, nn = nneg;

    // ---- negatives -> 8 registers once; pure-VALU scan --------------------
    float nr[8];
    #pragma unroll
    for (int c = 0; c < 8; ++c) {
        const int n = c * 64 + lane;
        nr[c] = (n < nn) ? neg[n] : 3.0e38f;  // sentinel -> contributes 0
    }
    float local = 0.f;
    for (int pi = w; pi < np; pi += 4) {      // positives striped over 4 waves
        const float dpm = pos[pi] + MARGIN;   // broadcast LDS read
        #pragma unroll
        for (int c = 0; c < 8; ++c)
            local += fmaxf(dpm - nr[c], 0.f);
    }

    // ---- block reduce + single device atomic ------------------------------
    #pragma unroll
    for (int off = 32; off > 0; off >>= 1) local += __shfl_down(local, off);
    if (lane == 0) wsum[w] = local;
    __syncthreads();
    if (tid == 0) {
        long long V = 0;
        #pragma unroll
        for (int t = 0; t < NTYPES; ++t) {
            long long c = cnt[t];
            V += c * c * (long long)(BSZ - c);
        }
        double bs = (double)wsum[0] + (double)wsum[1]
                  + (double)wsum[2] + (double)wsum[3];
        float contrib = (float)(bs / (double)V);
        if (a == 0) {
            const long long B3 = (long long)BSZ * BSZ * BSZ;
            contrib += (float)((double)(B3 - V) * (double)MARGIN / (double)V);
        }
        atomicAdd(out, contrib);              // plain relaxed device atomic
    }
}

extern "C" void kernel_launch(void* const* d_in, const int* in_sizes, int n_in,
                              void* d_out, int out_size, void* d_ws, size_t ws_size,
                              hipStream_t stream) {
    const int* types = (const int*)d_in[0];
    const float* emb = (const float*)d_in[1];
    float* out = (float*)d_out;

    float* G = (float*)d_ws;                          // 1 MB
    float* nrm = G + (size_t)BSZ * BSZ;               // 2 KB

    gram_kernel<<<256, 256, 0, stream>>>(emb, G, nrm, out);
    triplet_kernel<<<BSZ, 256, 0, stream>>>(G, nrm, types, out);
}

// Round 4
// 69.513 us; speedup vs baseline: 3.0153x; 1.0224x over previous
//
#include <hip/hip_runtime.h>
#include <hip/hip_bf16.h>

#define BSZ 512
#define DIM 768
#define NTYPES 16
#define MARGIN 1.0f
#define PITCH 776   // ushorts/row: 1552 B ≡ 97×16B (odd) -> b128 reads spread
                    // uniformly over the 8 4-bank groups ((m+q) mod 8) = conflict-free
#define CPITCH 18   // partial-C pitch: 72q+18r+m mod 32 -> 2-way max (free)

typedef short bf16x8 __attribute__((ext_vector_type(8)));
typedef float f32x4 __attribute__((ext_vector_type(4)));

// ---------------------------------------------------------------------------
// R4: same proven 3-dispatch structure as R3 (fill | gram | triplet), both
// kernels reshaped from the R3 budget post-mortem (~18us kernel work vs ~6us
// arithmetic -> latency exposure at 1 wave/SIMD in gram).
//
// gram_kernel: 256 blocks x 512 threads (8 waves = 2/SIMD), 32x32 tile,
// full K, split-K across wave halves.
//  - staging: thread t owns row r=t>>3, float4 cols s+8*it (s=t&7, it<24):
//    perfectly coalesced 128B segments, fp32 row norms accumulated for free
//    (per-thread partial -> shfl_xor 1/2/4 within the 8-lane row group ->
//    lane s==0 writes snrm[r]).  No global nrm array at all.
//  - MFMA: wave w -> quadrant quad=w&3 (wr=quad>>1, wc=quad&1), k-half
//    kh=w>>2 (kc in [12kh, 12kh+12)), even/odd accumulator chains for ILP.
//    Layouts verbatim from the verified baseline: A/B lane m=lane&15 holds
//    8 consecutive k at k0=8*(lane>>4); C/D col=m, row=4*(lane>>4)+reg.
//  - combine: kh=1 waves store partials to padded LDS pC; barrier; kh=0
//    waves add and write D = sqrt(max(ni+nj-2G, 0)) fp32 directly.
//    Numerics: bf16 gram + fp32 norms (R2-proven, absmax 0.0): d(a,a) is
//    ~0.3-0.8 instead of 0, but enters only as a positive against
//    d_neg≈sqrt(2*768)≈39 -> clamp(1.8-39)=0, same as reference's
//    clamp(1-39)=0.  Block 0 zeroes the poisoned out[0] (visibility proven).
//
// triplet_kernel: 512 blocks x 256 thr (2/CU), R3's proven ballot compaction
// + register-staged negative scan, minus the nrm load / LDS stage / sqrt
// (reads D directly).
// ---------------------------------------------------------------------------

__global__ __launch_bounds__(512) void gram_kernel(
    const float* __restrict__ emb,
    float* __restrict__ Dm,
    float* __restrict__ out)
{
    const int tid = threadIdx.x;
    const int blk = blockIdx.x;
    const int ti = blk >> 4, tj = blk & 15;
    const int i0 = ti * 32, j0 = tj * 32;

    if (blk == 0 && tid == 0) out[0] = 0.f;   // out is poisoned each launch

    __shared__ ushort sR[64][PITCH];          // rows 0-31: i-rows, 32-63: j-rows
    __shared__ float pC[4][16][CPITCH];       // kh=1 partial C tiles
    __shared__ float snrm[64];                // fp32 row norms

    // ---- stage: row r = tid>>3, cols s+8*it; coalesced 128B segments -------
    {
        const int r = tid >> 3;
        const int s = tid & 7;
        const int grow = (r < 32) ? (i0 + r) : (j0 + r - 32);
        const float* src = emb + (size_t)grow * DIM;
        float qn = 0.f;
        #pragma unroll 8
        for (int it = 0; it < 24; ++it) {
            const int c4 = s + 8 * it;        // float4 index 0..191
            const float4 v = *(const float4*)(src + c4 * 4);
            qn += v.x * v.x + v.y * v.y + v.z * v.z + v.w * v.w;
            __hip_bfloat162 h0 = __float22bfloat162_rn(make_float2(v.x, v.y));
            __hip_bfloat162 h1 = __float22bfloat162_rn(make_float2(v.z, v.w));
            unsigned u0, u1;
            __builtin_memcpy(&u0, &h0, 4);
            __builtin_memcpy(&u1, &h1, 4);
            *(uint2*)&sR[r][c4 * 4] = make_uint2(u0, u1);
        }
        qn += __shfl_xor(qn, 1);
        qn += __shfl_xor(qn, 2);
        qn += __shfl_xor(qn, 4);
        if (s == 0) snrm[r] = qn;             // fp32 row norm, free
    }
    __syncthreads();

    // ---- split-K MFMA: wave -> (quadrant, k-half) --------------------------
    const int lane = tid & 63;
    const int w = tid >> 6;                   // 0..7
    const int quad = w & 3;
    const int kh = w >> 2;                    // k-half 0/1
    const int wr = quad >> 1, wc = quad & 1;
    const int m = lane & 15;
    const int q = lane >> 4;

    const ushort* arow = &sR[wr * 16 + m][q * 8];
    const ushort* brow = &sR[32 + wc * 16 + m][q * 8];

    f32x4 acc_e = {0.f, 0.f, 0.f, 0.f};
    f32x4 acc_o = {0.f, 0.f, 0.f, 0.f};
    #pragma unroll
    for (int u = 0; u < 6; ++u) {
        const int kc = kh * 12 + 2 * u;
        const bf16x8 ae = *(const bf16x8*)(arow + kc * 32);
        const bf16x8 be = *(const bf16x8*)(brow + kc * 32);
        const bf16x8 ao = *(const bf16x8*)(arow + kc * 32 + 32);
        const bf16x8 bo = *(const bf16x8*)(brow + kc * 32 + 32);
        acc_e = __builtin_amdgcn_mfma_f32_16x16x32_bf16(ae, be, acc_e, 0, 0, 0);
        acc_o = __builtin_amdgcn_mfma_f32_16x16x32_bf16(ao, bo, acc_o, 0, 0, 0);
    }

    if (kh == 1) {
        #pragma unroll
        for (int r = 0; r < 4; ++r)
            pC[quad][4 * q + r][m] = acc_e[r] + acc_o[r];
    }
    __syncthreads();

    if (kh == 0) {
        const float nj = snrm[32 + wc * 16 + m];
        #pragma unroll
        for (int r = 0; r < 4; ++r) {
            const float g = acc_e[r] + acc_o[r] + pC[quad][4 * q + r][m];
            const float ni = snrm[wr * 16 + 4 * q + r];
            Dm[(size_t)(i0 + wr * 16 + 4 * q + r) * BSZ + (j0 + wc * 16 + m)] =
                sqrtf(fmaxf(ni + nj - 2.f * g, 0.f));
        }
    }
}

__global__ __launch_bounds__(256) void triplet_kernel(
    const float* __restrict__ Dm, const int* __restrict__ types,
    float* __restrict__ out)
{
    const int a = blockIdx.x;
    const int tid = threadIdx.x;
    const int lane = tid & 63;
    const int w = tid >> 6;

    __shared__ int   stypes[BSZ];
    __shared__ float pos[BSZ], neg[BSZ];
    __shared__ int   npos, nneg, cnt[NTYPES];
    __shared__ float wsum[4];

    // issue D-row loads early (overlap with stypes + barrier)
    float dval[2];
    #pragma unroll
    for (int jj = 0; jj < 2; ++jj)
        dval[jj] = Dm[(size_t)a * BSZ + jj * 256 + tid];

    if (tid == 0) { npos = 0; nneg = 0; }
    if (tid < NTYPES) cnt[tid] = 0;
    for (int j = tid; j < BSZ; j += 256) stypes[j] = types[j];
    __syncthreads();

    const int ta = stypes[a];
    for (int j = tid; j < BSZ; j += 256) atomicAdd(&cnt[stypes[j]], 1);

    // ---- ballot compaction (baseline-proven) -------------------------------
    #pragma unroll
    for (int jj = 0; jj < 2; ++jj) {
        const int j = jj * 256 + tid;
        const float d = dval[jj];
        const bool isp = (stypes[j] == ta);
        const unsigned long long mm = __ballot(isp);
        const unsigned long long below = mm & ((1ull << lane) - 1ull);
        const int cp = __popcll(mm);
        int basep = 0, basen = 0;
        if (lane == 0) {
            basep = atomicAdd(&npos, cp);
            basen = atomicAdd(&nneg, 64 - cp);
        }
        basep = __shfl(basep, 0);
        basen = __shfl(basen, 0);
        const int pb = (int)__popcll(below);
        if (isp) pos[basep + pb] = d;
        else     neg[basen + (lane - pb)] = d;
    }
    __syncthreads();
    const int np = npos, nn = nneg;

    // ---- negatives -> 8 registers once; pure-VALU scan ---------------------
    float nr[8];
    #pragma unroll
    for (int c = 0; c < 8; ++c) {
        const int n = c * 64 + lane;
        nr[c] = (n < nn) ? neg[n] : 3.0e38f;  // sentinel -> contributes 0
    }
    float local = 0.f;
    for (int pi = w; pi < np; pi += 4) {      // positives striped over 4 waves
        const float dpm = pos[pi] + MARGIN;   // broadcast LDS read
        #pragma unroll
        for (int c = 0; c < 8; ++c)
            local += fmaxf(dpm - nr[c], 0.f);
    }

    // ---- block reduce + single device atomic -------------------------------
    #pragma unroll
    for (int off = 32; off > 0; off >>= 1) local += __shfl_down(local, off);
    if (lane == 0) wsum[w] = local;
    __syncthreads();
    if (tid == 0) {
        long long V = 0;
        #pragma unroll
        for (int t = 0; t < NTYPES; ++t) {
            long long c = cnt[t];
            V += c * c * (long long)(BSZ - c);
        }
        double bs = (double)wsum[0] + (double)wsum[1]
                  + (double)wsum[2] + (double)wsum[3];
        float contrib = (float)(bs / (double)V);
        if (a == 0) {
            const long long B3 = (long long)BSZ * BSZ * BSZ;
            contrib += (float)((double)(B3 - V) * (double)MARGIN / (double)V);
        }
        atomicAdd(out, contrib);              // plain relaxed device atomic
    }
}

extern "C" void kernel_launch(void* const* d_in, const int* in_sizes, int n_in,
                              void* d_out, int out_size, void* d_ws, size_t ws_size,
                              hipStream_t stream) {
    const int* types = (const int*)d_in[0];
    const float* emb = (const float*)d_in[1];
    float* out = (float*)d_out;

    float* Dm = (float*)d_ws;                         // 1 MB distance matrix

    gram_kernel<<<256, 512, 0, stream>>>(emb, Dm, out);
    triplet_kernel<<<BSZ, 256, 0, stream>>>(Dm, types, out);
}